// Round 12
// baseline (2994.861 us; speedup 1.0000x reference)
//
#include <hip/hip_runtime.h>
#include <hip/hip_bf16.h>

typedef short bf16x8 __attribute__((ext_vector_type(8)));
typedef float f32x4 __attribute__((ext_vector_type(4)));

#define B_ 128
#define T_ 64
#define F_ 2048
#define N_ 1024
#define H_ 1024
#define C_ 22

__device__ __forceinline__ ushort f2bf(float f) {
    union { float f; unsigned u; } v; v.f = f;
    unsigned u = v.u;
    unsigned r = (u + 0x7FFFu + ((u >> 16) & 1u)) >> 16;
    return (ushort)r;
}
__device__ __forceinline__ float bf2f(ushort h) {
    union { unsigned u; float f; } v; v.u = ((unsigned)h) << 16;
    return v.f;
}

// ---------------- fp32 -> bf16 convert (vectorized) ----------------
__global__ __launch_bounds__(256) void cvt_f32_bf16(const float* __restrict__ in,
                                                    ushort* __restrict__ out, int n4) {
    int i = blockIdx.x * blockDim.x + threadIdx.x;
    if (i < n4) {
        float4 v = ((const float4*)in)[i];
        ushort4 o;
        o.x = f2bf(v.x); o.y = f2bf(v.y); o.z = f2bf(v.z); o.w = f2bf(v.w);
        ((ushort4*)out)[i] = o;
    }
}

// Wc [22][1024] f32 -> [32][1024] bf16, zero-padded rows 22..31
__global__ __launch_bounds__(256) void cvt_wc(const float* __restrict__ Wc,
                                              ushort* __restrict__ Wcb) {
    int i = blockIdx.x * 256 + threadIdx.x;   // 32768 total
    int row = i >> 10;
    Wcb[i] = (row < C_) ? f2bf(Wc[i]) : (ushort)0;
}

// ---------------- async global->LDS, 16B per lane ----------------
__device__ __forceinline__ void gload16(const void* g, void* l) {
    __builtin_amdgcn_global_load_lds(
        (const __attribute__((address_space(1))) unsigned int*)g,
        (__attribute__((address_space(3))) unsigned int*)l, 16, 0, 0);
}

// ---------------- bf16 TN GEMM: C[m][n] = act(A[m][:] . B[n][:] + bias) ----------------
template<int K, bool RELU>
__global__ __launch_bounds__(256) void gemm_bt(const ushort* __restrict__ A,
                                               const ushort* __restrict__ Bm,
                                               const float* __restrict__ bias1,
                                               const float* __restrict__ bias2,
                                               ushort* __restrict__ C,
                                               int Nt, int Nn) {
    __shared__ ushort sA[128 * 32];
    __shared__ ushort sB[128 * 32];
    const int tid = threadIdx.x;
    const int lane = tid & 63, wv = tid >> 6;
    const int tm = blockIdx.x / Nt, tn = blockIdx.x % Nt;
    const int wm = wv >> 1, wn = wv & 1;

    const ushort* gA = A + (size_t)(tm * 128 + (tid >> 2)) * K + (tid & 3) * 8;
    const ushort* gB = Bm + (size_t)(tn * 128 + (tid >> 2)) * K + (tid & 3) * 8;
    char* lAb = (char*)sA + wv * 1024;
    char* lBb = (char*)sB + wv * 1024;

    f32x4 acc[4][4] = {};

    for (int kt = 0; kt < K / 32; kt++) {
        const ushort* a0 = gA + kt * 32;
        const ushort* b0 = gB + kt * 32;
        gload16(a0, lAb);
        gload16(a0 + 64 * K, lAb + 4096);
        gload16(b0, lBb);
        gload16(b0 + 64 * K, lBb + 4096);
        __syncthreads();

        bf16x8 af[4], bfv[4];
#pragma unroll
        for (int i = 0; i < 4; i++)
            af[i] = *(const bf16x8*)&sA[(wm * 64 + i * 16 + (lane & 15)) * 32 + (lane >> 4) * 8];
#pragma unroll
        for (int j = 0; j < 4; j++)
            bfv[j] = *(const bf16x8*)&sB[(wn * 64 + j * 16 + (lane & 15)) * 32 + (lane >> 4) * 8];
#pragma unroll
        for (int i = 0; i < 4; i++)
#pragma unroll
            for (int j = 0; j < 4; j++)
                acc[i][j] = __builtin_amdgcn_mfma_f32_16x16x32_bf16(af[i], bfv[j], acc[i][j], 0, 0, 0);
        __syncthreads();
    }

#pragma unroll
    for (int j = 0; j < 4; j++) {
        int n = tn * 128 + wn * 64 + j * 16 + (lane & 15);
        float bias = bias1[n] + (bias2 ? bias2[n] : 0.f);
#pragma unroll
        for (int i = 0; i < 4; i++) {
            int mbase = tm * 128 + wm * 64 + i * 16 + (lane >> 4) * 4;
#pragma unroll
            for (int r = 0; r < 4; r++) {
                float v = acc[i][j][r] + bias;
                if (RELU) v = v > 0.f ? v : 0.f;
                C[(size_t)(mbase + r) * Nn + n] = f2bf(v);
            }
        }
    }
}

// ---------- persistent LSTM recurrence: r9 geometry + XCD-local L2 sync (hang-proof) ----------
// 256 blocks x 512 thr (2 waves/SIMD), blk = hb*8 + bt: group = 32 blocks, all == bt (mod 8)
// -> same XCD under round-robin dispatch. Leader (blk==bt) VERIFIES via HW_REG_XCC_ID table
// (bounded spin) and publishes a per-group decision -> consistent protocol, no mixed-mode.
// Fast path (verified local): h stores + flag posts at WORKGROUP scope (land in shared L2);
// polls via atomic fetch_add(ptr,0) which executes at the L2 point (this is the r10 fix:
// sc0 loads read at/above L2 and missed dirty-L2 flags -> deadlock).
// Hang-proofing: producers ALSO post an agent-scope flag copy (fire-and-forget); consumers
// cap L2 poll sweeps and degrade permanently to the r9-proven agent flags. Worst case = r9.
__global__ __launch_bounds__(512, 2) void lstm_persist(ushort* __restrict__ hs,
                                                       const ushort* __restrict__ xg,
                                                       const ushort* __restrict__ Whh,
                                                       unsigned* __restrict__ flagL,
                                                       unsigned* __restrict__ flagA,
                                                       unsigned* __restrict__ xcctab,
                                                       unsigned* __restrict__ decis) {
    const int tid = threadIdx.x;
    const int lane = tid & 63;
    const int wv = tid >> 6;                 // 0..7
    const int g = wv >> 1;                   // gate
    const int ch = wv & 1;                   // col half (16 cols)
    const int blk = (int)blockIdx.x;
    const int bt = blk & 7;                  // batch tile (16 rows); == XCD id if round-robin
    const int hb = blk >> 3;                 // hid tile (32 cols)
    const int batch0 = bt * 16;
    const int hid0 = hb * 32;

    __shared__ int s_local;

    // ---- startup: leader verifies same-XCD placement, publishes decision ----
    unsigned myxcc;
    asm volatile("s_getreg_b32 %0, hwreg(HW_REG_XCC_ID)" : "=s"(myxcc));
    if (tid == 0)
        __hip_atomic_store(&xcctab[blk], myxcc + 1, __ATOMIC_RELAXED, __HIP_MEMORY_SCOPE_AGENT);
    if (blk == bt && wv == 0) {              // leader block of this group
        unsigned ok = 2u;                    // default: fallback
        for (int it = 0; it < 100000; ++it) {
            unsigned e = __hip_atomic_load(&xcctab[(lane & 31) * 8 + bt],
                                           __ATOMIC_RELAXED, __HIP_MEMORY_SCOPE_AGENT);
            if (__ballot(e == 0u) == 0ull) {
                ok = (__ballot(e != myxcc + 1) == 0ull) ? 1u : 2u;
                break;
            }
            __builtin_amdgcn_s_sleep(2);
        }
        if (lane == 0)
            __hip_atomic_store(&decis[bt], ok, __ATOMIC_RELAXED, __HIP_MEMORY_SCOPE_AGENT);
    }
    if (wv == 0) {
        unsigned dec;
        for (;;) {
            dec = __hip_atomic_load(&decis[bt], __ATOMIC_RELAXED, __HIP_MEMORY_SCOPE_AGENT);
            if (__ballot(dec == 0u) == 0ull) break;
            __builtin_amdgcn_s_sleep(2);
        }
        if (lane == 0) s_local = (dec == 1u);
    }
    __syncthreads();
    const bool local = (s_local != 0);

    // Whh B-fragments: rows g*H + hid0 + ch*16 + (lane&15), k = (lane>>4)*8 + ks*32
    bf16x8 breg[32];
    {
        const ushort* br = Whh + (size_t)(g * H_ + hid0 + ch * 16 + (lane & 15)) * H_
                         + ((lane >> 4) * 8);
#pragma unroll
        for (int ks = 0; ks < 32; ks++) breg[ks] = *(const bf16x8*)(br + ks * 32);
#pragma unroll
        for (int ks = 0; ks < 32; ks++) asm volatile("" : "+v"(breg[ks]));
    }

    __shared__ float lg[4][16][32];          // [gate][batch row][hid col]

    const int grow = tid >> 5;               // 0..15 batch row within tile
    const int gcol = tid & 31;               // 0..31 hid col within tile
    const int b = batch0 + grow;
    const int jj = hid0 + gcol;
    const ushort* xrow = xg + ((size_t)(b * T_) << 12) + jj;   // advance 4096/step
    float c0 = 0.f;

    // poll addresses: this batch-tile group's members are blocks hb'*8 + bt
    unsigned* fLp = &flagL[(((lane & 31) * 8) + bt) * 16];
    unsigned* fAp = &flagA[(((lane & 31) * 8) + bt) * 16];
    bool useA = !local;                      // degraded (or fallback) -> agent flags

    for (int t = 0; t < T_; t++) {
        // xg loads issued early (HBM latency hides under h-load + MFMA)
        const ushort* xr = xrow + ((size_t)t << 12);
        ushort xi = xr[0], xf = xr[1024], xgv = xr[2048], xo = xr[3072];

        // gates_pre = h[t](16 rows) @ Whh_tile^T
        const ushort* ar = hs + (size_t)t * (B_ * H_)
                         + (size_t)(batch0 + (lane & 15)) * H_ + ((lane >> 4) * 8);
        f32x4 acc = {};
#pragma unroll
        for (int ks = 0; ks < 32; ks++) {
            bf16x8 a0 = *(const bf16x8*)(ar + ks * 32);
            acc = __builtin_amdgcn_mfma_f32_16x16x32_bf16(a0, breg[ks], acc, 0, 0, 0);
        }
#pragma unroll
        for (int r = 0; r < 4; r++)
            lg[g][(lane >> 4) * 4 + r][ch * 16 + (lane & 15)] = acc[r];
        __syncthreads();

        // gate math: 1 (row,col) cell per thread
        {
            float pi = bf2f(xi)  + lg[0][grow][gcol];
            float pf = bf2f(xf)  + lg[1][grow][gcol];
            float pg = bf2f(xgv) + lg[2][grow][gcol];
            float po = bf2f(xo)  + lg[3][grow][gcol];
            float si = 1.f / (1.f + expf(-pi));
            float sf = 1.f / (1.f + expf(-pf));
            float tg = tanhf(pg);
            float so = 1.f / (1.f + expf(-po));
            c0 = sf * c0 + si * tg;
            ushort hbf = f2bf(so * tanhf(c0));
            uint other = __shfl_xor((uint)hbf, 1);           // neighbor col^1 (same wave)
            if ((lane & 1) == 0) {
                uint hp = (uint)hbf | (other << 16);
                unsigned* hp32 = (unsigned*)(hs + (size_t)(t + 1) * (B_ * H_)
                                             + (size_t)b * H_ + jj);
                if (local)   // same-XCD (verified): plain store -> shared L2
                    __hip_atomic_store(hp32, hp, __ATOMIC_RELAXED, __HIP_MEMORY_SCOPE_WORKGROUP);
                else         // cross-XCD: write-through to L3 (round-3/8/9 proven)
                    __hip_atomic_store(hp32, hp, __ATOMIC_RELAXED, __HIP_MEMORY_SCOPE_AGENT);
            }
        }
        asm volatile("s_waitcnt vmcnt(0)" ::: "memory");  // h stores at L2/L3 before barrier
        __syncthreads();

        if (t < T_ - 1) {
            if (tid == 0) {
                if (local)
                    __hip_atomic_store(&flagL[blk * 16], (unsigned)(t + 1),
                                       __ATOMIC_RELAXED, __HIP_MEMORY_SCOPE_WORKGROUP);
                // agent copy always posted (fire-and-forget): hang-proof degradation target
                __hip_atomic_store(&flagA[blk * 16], (unsigned)(t + 1),
                                   __ATOMIC_RELAXED, __HIP_MEMORY_SCOPE_AGENT);
            }
            if (wv == 0) {
                if (!useA) {
                    // fast poll: atomic RMW executes at the shared-L2 point
                    int sweeps = 0;
                    for (;;) {
                        unsigned f = __hip_atomic_fetch_add(fLp, 0u,
                                         __ATOMIC_RELAXED, __HIP_MEMORY_SCOPE_WORKGROUP);
                        if (__ballot(f < (unsigned)(t + 1)) == 0ull) break;
                        if (++sweeps > 20000) { useA = true; break; }
                        __builtin_amdgcn_s_sleep(1);
                    }
                }
                if (useA) {
                    for (;;) {
                        unsigned f = __hip_atomic_load(fAp,
                                         __ATOMIC_RELAXED, __HIP_MEMORY_SCOPE_AGENT);
                        if (__ballot(f < (unsigned)(t + 1)) == 0ull) break;
                        __builtin_amdgcn_s_sleep(1);
                    }
                }
            }
            __syncthreads();
        }
    }
}

// ---------------- final classifier via MFMA: out[8192][22] = hs @ Wcb^T + bc ----------------
__global__ __launch_bounds__(256) void scores_mfma(const ushort* __restrict__ hs,
                                                   const ushort* __restrict__ Wcb,
                                                   const float* __restrict__ bc,
                                                   float* __restrict__ out) {
    const int tid = threadIdx.x, lane = tid & 63, w = tid >> 6;
    const int r0 = blockIdx.x * 64 + w * 16;
    const int rr = r0 + (lane & 15);          // output row = b*64 + t
    const int b = rr >> 6, t = rr & 63;
    const ushort* arow = hs + (size_t)(t + 1) * (B_ * H_) + (size_t)b * H_ + ((lane >> 4) * 8);
    const ushort* brow0 = Wcb + (size_t)(lane & 15) * H_ + ((lane >> 4) * 8);
    const ushort* brow1 = brow0 + 16 * H_;

    f32x4 acc0 = {}, acc1 = {};
#pragma unroll
    for (int ks = 0; ks < 32; ks++) {
        bf16x8 a  = *(const bf16x8*)(arow + ks * 32);
        bf16x8 p0 = *(const bf16x8*)(brow0 + ks * 32);
        bf16x8 p1 = *(const bf16x8*)(brow1 + ks * 32);
        acc0 = __builtin_amdgcn_mfma_f32_16x16x32_bf16(a, p0, acc0, 0, 0, 0);
        acc1 = __builtin_amdgcn_mfma_f32_16x16x32_bf16(a, p1, acc1, 0, 0, 0);
    }
#pragma unroll
    for (int nf = 0; nf < 2; nf++) {
        int c = nf * 16 + (lane & 15);
        if (c < C_) {
            float bias = bc[c];
            f32x4 acc = nf ? acc1 : acc0;
#pragma unroll
            for (int r = 0; r < 4; r++) {
                int row = r0 + (lane >> 4) * 4 + r;
                out[(size_t)row * C_ + c] = acc[r] + bias;
            }
        }
    }
}

extern "C" void kernel_launch(void* const* d_in, const int* in_sizes, int n_in,
                              void* d_out, int out_size, void* d_ws, size_t ws_size,
                              hipStream_t stream) {
    const float* x = (const float*)d_in[0];
    const float* W1 = (const float*)d_in[1];
    const float* b1 = (const float*)d_in[2];
    const float* W_ih = (const float*)d_in[3];
    const float* b_ih = (const float*)d_in[4];
    const float* W_hh = (const float*)d_in[5];
    const float* b_hh = (const float*)d_in[6];
    const float* Wc = (const float*)d_in[7];
    const float* bc = (const float*)d_in[8];
    float* out = (float*)d_out;

    char* ws = (char*)d_ws;
    ushort* Xb   = (ushort*)(ws);                 // 33,554,432 B  [8192][2048] bf16
    ushort* W1b  = (ushort*)(ws + 33554432);      //  4,194,304 B
    ushort* Wihb = (ushort*)(ws + 37748736);      //  8,388,608 B
    ushort* Whhb = (ushort*)(ws + 46137344);      //  8,388,608 B
    ushort* z    = (ushort*)(ws + 54525952);      // 16,777,216 B  [8192][1024]
    ushort* xg   = (ushort*)(ws + 71303168);      // 67,108,864 B  [8192][4096]
    ushort* hs   = (ushort*)(ws + 138412032);     // 17,039,360 B  [65][128][1024]
    ushort* Wcb  = (ushort*)(ws + 155451392);     //     65,536 B  [32][1024] bf16
    unsigned* flagL  = (unsigned*)(ws + 155516928); //   16,384 B  [256] padded u32
    unsigned* flagA  = (unsigned*)(ws + 155533312); //   16,384 B  [256] padded u32
    unsigned* xcctab = (unsigned*)(ws + 155549696); //    1,024 B  [256] u32
    unsigned* decis  = (unsigned*)(ws + 155550720); //    1,024 B  [8] u32 (padded)
    // total ws use: ~155.6 MB

    hipMemsetAsync(hs, 0, (size_t)B_ * H_ * sizeof(ushort), stream);   // h0 = 0
    hipMemsetAsync(flagL, 0, 16384, stream);
    hipMemsetAsync(flagA, 0, 16384, stream);
    hipMemsetAsync(xcctab, 0, 1024, stream);
    hipMemsetAsync(decis, 0, 1024, stream);

    cvt_f32_bf16<<<16384, 256, 0, stream>>>(x, Xb, 4194304);
    cvt_f32_bf16<<<2048, 256, 0, stream>>>(W1, W1b, 524288);
    cvt_f32_bf16<<<4096, 256, 0, stream>>>(W_ih, Wihb, 1048576);
    cvt_f32_bf16<<<4096, 256, 0, stream>>>(W_hh, Whhb, 1048576);
    cvt_wc<<<128, 256, 0, stream>>>(Wc, Wcb);

    // z = relu(x @ W1^T + b1)                 M=8192 N=1024 K=2048
    gemm_bt<2048, true><<<512, 256, 0, stream>>>(Xb, W1b, b1, nullptr, z, 8, 1024);
    // xg = z @ W_ih^T + (b_ih + b_hh)         M=8192 N=4096 K=1024
    gemm_bt<1024, false><<<2048, 256, 0, stream>>>(z, Wihb, b_ih, b_hh, xg, 32, 4096);

    // recurrence: dual-protocol persistent kernel, L2-local sync when placement verified
    lstm_persist<<<256, 512, 0, stream>>>(hs, xg, Whhb, flagL, flagA, xcctab, decis);

    scores_mfma<<<128, 256, 0, stream>>>(hs, Wcb, bc, out);
}

// Round 13
// 885.617 us; speedup vs baseline: 3.3817x; 3.3817x over previous
//
#include <hip/hip_runtime.h>
#include <hip/hip_bf16.h>

typedef short bf16x8 __attribute__((ext_vector_type(8)));
typedef float f32x4 __attribute__((ext_vector_type(4)));

#define B_ 128
#define T_ 64
#define F_ 2048
#define N_ 1024
#define H_ 1024
#define C_ 22

__device__ __forceinline__ ushort f2bf(float f) {
    union { float f; unsigned u; } v; v.f = f;
    unsigned u = v.u;
    unsigned r = (u + 0x7FFFu + ((u >> 16) & 1u)) >> 16;
    return (ushort)r;
}
__device__ __forceinline__ float bf2f(ushort h) {
    union { unsigned u; float f; } v; v.u = ((unsigned)h) << 16;
    return v.f;
}

// ---------------- fp32 -> bf16 convert (vectorized) ----------------
__global__ __launch_bounds__(256) void cvt_f32_bf16(const float* __restrict__ in,
                                                    ushort* __restrict__ out, int n4) {
    int i = blockIdx.x * blockDim.x + threadIdx.x;
    if (i < n4) {
        float4 v = ((const float4*)in)[i];
        ushort4 o;
        o.x = f2bf(v.x); o.y = f2bf(v.y); o.z = f2bf(v.z); o.w = f2bf(v.w);
        ((ushort4*)out)[i] = o;
    }
}

// Wc [22][1024] f32 -> [32][1024] bf16, zero-padded rows 22..31
__global__ __launch_bounds__(256) void cvt_wc(const float* __restrict__ Wc,
                                              ushort* __restrict__ Wcb) {
    int i = blockIdx.x * 256 + threadIdx.x;   // 32768 total
    int row = i >> 10;
    Wcb[i] = (row < C_) ? f2bf(Wc[i]) : (ushort)0;
}

// ---------------- async global->LDS, 16B per lane ----------------
__device__ __forceinline__ void gload16(const void* g, void* l) {
    __builtin_amdgcn_global_load_lds(
        (const __attribute__((address_space(1))) unsigned int*)g,
        (__attribute__((address_space(3))) unsigned int*)l, 16, 0, 0);
}

// ---------------- bf16 TN GEMM: C[m][n] = act(A[m][:] . B[n][:] + bias) ----------------
template<int K, bool RELU>
__global__ __launch_bounds__(256) void gemm_bt(const ushort* __restrict__ A,
                                               const ushort* __restrict__ Bm,
                                               const float* __restrict__ bias1,
                                               const float* __restrict__ bias2,
                                               ushort* __restrict__ C,
                                               int Nt, int Nn) {
    __shared__ ushort sA[128 * 32];
    __shared__ ushort sB[128 * 32];
    const int tid = threadIdx.x;
    const int lane = tid & 63, wv = tid >> 6;
    const int tm = blockIdx.x / Nt, tn = blockIdx.x % Nt;
    const int wm = wv >> 1, wn = wv & 1;

    const ushort* gA = A + (size_t)(tm * 128 + (tid >> 2)) * K + (tid & 3) * 8;
    const ushort* gB = Bm + (size_t)(tn * 128 + (tid >> 2)) * K + (tid & 3) * 8;
    char* lAb = (char*)sA + wv * 1024;
    char* lBb = (char*)sB + wv * 1024;

    f32x4 acc[4][4] = {};

    for (int kt = 0; kt < K / 32; kt++) {
        const ushort* a0 = gA + kt * 32;
        const ushort* b0 = gB + kt * 32;
        gload16(a0, lAb);
        gload16(a0 + 64 * K, lAb + 4096);
        gload16(b0, lBb);
        gload16(b0 + 64 * K, lBb + 4096);
        __syncthreads();

        bf16x8 af[4], bfv[4];
#pragma unroll
        for (int i = 0; i < 4; i++)
            af[i] = *(const bf16x8*)&sA[(wm * 64 + i * 16 + (lane & 15)) * 32 + (lane >> 4) * 8];
#pragma unroll
        for (int j = 0; j < 4; j++)
            bfv[j] = *(const bf16x8*)&sB[(wn * 64 + j * 16 + (lane & 15)) * 32 + (lane >> 4) * 8];
#pragma unroll
        for (int i = 0; i < 4; i++)
#pragma unroll
            for (int j = 0; j < 4; j++)
                acc[i][j] = __builtin_amdgcn_mfma_f32_16x16x32_bf16(af[i], bfv[j], acc[i][j], 0, 0, 0);
        __syncthreads();
    }

#pragma unroll
    for (int j = 0; j < 4; j++) {
        int n = tn * 128 + wn * 64 + j * 16 + (lane & 15);
        float bias = bias1[n] + (bias2 ? bias2[n] : 0.f);
#pragma unroll
        for (int i = 0; i < 4; i++) {
            int mbase = tm * 128 + wm * 64 + i * 16 + (lane >> 4) * 4;
#pragma unroll
            for (int r = 0; r < 4; r++) {
                float v = acc[i][j][r] + bias;
                if (RELU) v = v > 0.f ? v : 0.f;
                C[(size_t)(mbase + r) * Nn + n] = f2bf(v);
            }
        }
    }
}

// ---------- persistent LSTM recurrence: 2 co-resident chain-blocks per CU ----------
// 512 blocks x 256 thr, __launch_bounds__(256,2) -> 2 blocks/CU co-resident.
// Block = 16 batch rows x 16 hid cols; 4 waves, wave = gate (32 MFMAs/wave/step).
// blk = hb*8 + bt: adjacent block IDs serve DIFFERENT batch-tile groups -> the two
// blocks sharing a CU are (likely) from independent recurrence chains, so each chain's
// sync latency (flag RTT, h write-ACK) hides under the other chain's MFMA/gate work.
// Sync protocol byte-identical to round 3/8 (all agent-scope, padded flags, s_sleep):
// correctness never depends on placement or scheduling (G16); only speed does.
__global__ __launch_bounds__(256, 2) void lstm_persist(ushort* __restrict__ hs,
                                                       const ushort* __restrict__ xg,
                                                       const ushort* __restrict__ Whh,
                                                       unsigned* __restrict__ flags) {
    const int tid = threadIdx.x;
    const int lane = tid & 63;
    const int g = tid >> 6;                  // wave index == gate index
    const int blk = (int)blockIdx.x;
    const int bt = blk & 7;                  // batch tile (16 rows) / sync group
    const int hb = blk >> 3;                 // hid tile (16 cols), 0..63
    const int batch0 = bt * 16;
    const int hid0 = hb * 16;

    // Whh B-fragments for gate g, cols hid0..hid0+15: rows g*H + hid0 + (lane&15)
    bf16x8 breg[32];
    {
        const ushort* br = Whh + (size_t)(g * H_ + hid0 + (lane & 15)) * H_ + ((lane >> 4) * 8);
#pragma unroll
        for (int ks = 0; ks < 32; ks++) breg[ks] = *(const bf16x8*)(br + ks * 32);
#pragma unroll
        for (int ks = 0; ks < 32; ks++) asm volatile("" : "+v"(breg[ks]));
    }

    __shared__ float lg[4][16][16];          // [gate][batch row][hid col]

    const int grow = tid >> 4;               // 0..15 batch row within tile
    const int gcol = tid & 15;               // 0..15 hid col within tile
    const int b = batch0 + grow;
    const int jj = hid0 + gcol;
    const ushort* xrow = xg + ((size_t)(b * T_) << 12) + jj;   // advance 4096/step
    float c0 = 0.f;

    for (int t = 0; t < T_; t++) {
        // xg loads issued early (L3/HBM latency hides under h-load + MFMA)
        const ushort* xr = xrow + ((size_t)t << 12);
        ushort xi = xr[0], xf = xr[1024], xgv = xr[2048], xo = xr[3072];

        // gates_pre = h[t](16 rows) @ Whh_tile^T   (32 MFMAs)
        const ushort* ar = hs + (size_t)t * (B_ * H_)
                         + (size_t)(batch0 + (lane & 15)) * H_ + ((lane >> 4) * 8);
        f32x4 acc = {};
#pragma unroll
        for (int ks = 0; ks < 32; ks++) {
            bf16x8 a0 = *(const bf16x8*)(ar + ks * 32);
            acc = __builtin_amdgcn_mfma_f32_16x16x32_bf16(a0, breg[ks], acc, 0, 0, 0);
        }
#pragma unroll
        for (int r = 0; r < 4; r++)
            lg[g][(lane >> 4) * 4 + r][lane & 15] = acc[r];
        __syncthreads();

        // gate math: 1 (row,col) cell per thread
        {
            float pi = bf2f(xi)  + lg[0][grow][gcol];
            float pf = bf2f(xf)  + lg[1][grow][gcol];
            float pg = bf2f(xgv) + lg[2][grow][gcol];
            float po = bf2f(xo)  + lg[3][grow][gcol];
            float si = 1.f / (1.f + expf(-pi));
            float sf = 1.f / (1.f + expf(-pf));
            float tg = tanhf(pg);
            float so = 1.f / (1.f + expf(-po));
            c0 = sf * c0 + si * tg;
            ushort hbf = f2bf(so * tanhf(c0));
            uint other = __shfl_xor((uint)hbf, 1);           // neighbor col^1 (same wave)
            if ((gcol & 1) == 0) {
                uint hp = (uint)hbf | (other << 16);
                unsigned* hp32 = (unsigned*)(hs + (size_t)(t + 1) * (B_ * H_)
                                             + (size_t)b * H_ + jj);
                // agent-scope store: write-through, visible to all XCDs (r3/r8 proven)
                __hip_atomic_store(hp32, hp, __ATOMIC_RELAXED, __HIP_MEMORY_SCOPE_AGENT);
            }
        }
        asm volatile("s_waitcnt vmcnt(0)" ::: "memory");  // h stores ACK'd before barrier
        __syncthreads();

        if (t < T_ - 1) {
            if (tid == 0)
                __hip_atomic_store(&flags[blk * 16], (unsigned)(t + 1),
                                   __ATOMIC_RELAXED, __HIP_MEMORY_SCOPE_AGENT);
            if (g == 0) {
                // poll the 64 flags of this batch-tile's group (blocks hb'*8 + bt)
                for (;;) {
                    unsigned f = __hip_atomic_load(&flags[(lane * 8 + bt) * 16],
                                                   __ATOMIC_RELAXED, __HIP_MEMORY_SCOPE_AGENT);
                    if (__ballot(f < (unsigned)(t + 1)) == 0ull) break;
                    __builtin_amdgcn_s_sleep(1);
                }
            }
            __syncthreads();
        }
    }
}

// ---------------- final classifier via MFMA: out[8192][22] = hs @ Wcb^T + bc ----------------
__global__ __launch_bounds__(256) void scores_mfma(const ushort* __restrict__ hs,
                                                   const ushort* __restrict__ Wcb,
                                                   const float* __restrict__ bc,
                                                   float* __restrict__ out) {
    const int tid = threadIdx.x, lane = tid & 63, w = tid >> 6;
    const int r0 = blockIdx.x * 64 + w * 16;
    const int rr = r0 + (lane & 15);          // output row = b*64 + t
    const int b = rr >> 6, t = rr & 63;
    const ushort* arow = hs + (size_t)(t + 1) * (B_ * H_) + (size_t)b * H_ + ((lane >> 4) * 8);
    const ushort* brow0 = Wcb + (size_t)(lane & 15) * H_ + ((lane >> 4) * 8);
    const ushort* brow1 = brow0 + 16 * H_;

    f32x4 acc0 = {}, acc1 = {};
#pragma unroll
    for (int ks = 0; ks < 32; ks++) {
        bf16x8 a  = *(const bf16x8*)(arow + ks * 32);
        bf16x8 p0 = *(const bf16x8*)(brow0 + ks * 32);
        bf16x8 p1 = *(const bf16x8*)(brow1 + ks * 32);
        acc0 = __builtin_amdgcn_mfma_f32_16x16x32_bf16(a, p0, acc0, 0, 0, 0);
        acc1 = __builtin_amdgcn_mfma_f32_16x16x32_bf16(a, p1, acc1, 0, 0, 0);
    }
#pragma unroll
    for (int nf = 0; nf < 2; nf++) {
        int c = nf * 16 + (lane & 15);
        if (c < C_) {
            float bias = bc[c];
            f32x4 acc = nf ? acc1 : acc0;
#pragma unroll
            for (int r = 0; r < 4; r++) {
                int row = r0 + (lane >> 4) * 4 + r;
                out[(size_t)row * C_ + c] = acc[r] + bias;
            }
        }
    }
}

extern "C" void kernel_launch(void* const* d_in, const int* in_sizes, int n_in,
                              void* d_out, int out_size, void* d_ws, size_t ws_size,
                              hipStream_t stream) {
    const float* x = (const float*)d_in[0];
    const float* W1 = (const float*)d_in[1];
    const float* b1 = (const float*)d_in[2];
    const float* W_ih = (const float*)d_in[3];
    const float* b_ih = (const float*)d_in[4];
    const float* W_hh = (const float*)d_in[5];
    const float* b_hh = (const float*)d_in[6];
    const float* Wc = (const float*)d_in[7];
    const float* bc = (const float*)d_in[8];
    float* out = (float*)d_out;

    char* ws = (char*)d_ws;
    ushort* Xb   = (ushort*)(ws);                 // 33,554,432 B  [8192][2048] bf16
    ushort* W1b  = (ushort*)(ws + 33554432);      //  4,194,304 B
    ushort* Wihb = (ushort*)(ws + 37748736);      //  8,388,608 B
    ushort* Whhb = (ushort*)(ws + 46137344);      //  8,388,608 B
    ushort* z    = (ushort*)(ws + 54525952);      // 16,777,216 B  [8192][1024]
    ushort* xg   = (ushort*)(ws + 71303168);      // 67,108,864 B  [8192][4096]
    ushort* hs   = (ushort*)(ws + 138412032);     // 17,039,360 B  [65][128][1024]
    ushort* Wcb  = (ushort*)(ws + 155451392);     //     65,536 B  [32][1024] bf16
    unsigned* flags = (unsigned*)(ws + 155516928);//     32,768 B  [512] padded u32 (64B/flag)
    // total ws use: ~155.6 MB

    hipMemsetAsync(hs, 0, (size_t)B_ * H_ * sizeof(ushort), stream);   // h0 = 0
    hipMemsetAsync(flags, 0, 32768, stream);                           // barrier flags = 0

    cvt_f32_bf16<<<16384, 256, 0, stream>>>(x, Xb, 4194304);
    cvt_f32_bf16<<<2048, 256, 0, stream>>>(W1, W1b, 524288);
    cvt_f32_bf16<<<4096, 256, 0, stream>>>(W_ih, Wihb, 1048576);
    cvt_f32_bf16<<<4096, 256, 0, stream>>>(W_hh, Whhb, 1048576);
    cvt_wc<<<128, 256, 0, stream>>>(Wc, Wcb);

    // z = relu(x @ W1^T + b1)                 M=8192 N=1024 K=2048
    gemm_bt<2048, true><<<512, 256, 0, stream>>>(Xb, W1b, b1, nullptr, z, 8, 1024);
    // xg = z @ W_ih^T + (b_ih + b_hh)         M=8192 N=4096 K=1024
    gemm_bt<1024, false><<<2048, 256, 0, stream>>>(z, Wihb, b_ih, b_hh, xg, 32, 4096);

    // recurrence: 512 blocks x 256 thr, 2 chain-blocks per CU (SMT-style latency hiding)
    lstm_persist<<<512, 256, 0, stream>>>(hs, xg, Whhb, flags);

    scores_mfma<<<128, 256, 0, stream>>>(hs, Wcb, bc, out);
}

// Round 14
// 821.299 us; speedup vs baseline: 3.6465x; 1.0783x over previous
//
#include <hip/hip_runtime.h>
#include <hip/hip_bf16.h>

typedef short bf16x8 __attribute__((ext_vector_type(8)));
typedef float f32x4 __attribute__((ext_vector_type(4)));

#define B_ 128
#define T_ 64
#define F_ 2048
#define N_ 1024
#define H_ 1024
#define C_ 22

__device__ __forceinline__ ushort f2bf(float f) {
    union { float f; unsigned u; } v; v.f = f;
    unsigned u = v.u;
    unsigned r = (u + 0x7FFFu + ((u >> 16) & 1u)) >> 16;
    return (ushort)r;
}
__device__ __forceinline__ float bf2f(ushort h) {
    union { unsigned u; float f; } v; v.u = ((unsigned)h) << 16;
    return v.f;
}

// ---------------- fp32 -> bf16 convert (vectorized) ----------------
__global__ __launch_bounds__(256) void cvt_f32_bf16(const float* __restrict__ in,
                                                    ushort* __restrict__ out, int n4) {
    int i = blockIdx.x * blockDim.x + threadIdx.x;
    if (i < n4) {
        float4 v = ((const float4*)in)[i];
        ushort4 o;
        o.x = f2bf(v.x); o.y = f2bf(v.y); o.z = f2bf(v.z); o.w = f2bf(v.w);
        ((ushort4*)out)[i] = o;
    }
}

// Wc [22][1024] f32 -> [32][1024] bf16, zero-padded rows 22..31
__global__ __launch_bounds__(256) void cvt_wc(const float* __restrict__ Wc,
                                              ushort* __restrict__ Wcb) {
    int i = blockIdx.x * 256 + threadIdx.x;   // 32768 total
    int row = i >> 10;
    Wcb[i] = (row < C_) ? f2bf(Wc[i]) : (ushort)0;
}

// ---------------- async global->LDS, 16B per lane ----------------
__device__ __forceinline__ void gload16(const void* g, void* l) {
    __builtin_amdgcn_global_load_lds(
        (const __attribute__((address_space(1))) unsigned int*)g,
        (__attribute__((address_space(3))) unsigned int*)l, 16, 0, 0);
}

// ---------------- bf16 TN GEMM: C[m][n] = act(A[m][:] . B[n][:] + bias) ----------------
template<int K, bool RELU>
__global__ __launch_bounds__(256) void gemm_bt(const ushort* __restrict__ A,
                                               const ushort* __restrict__ Bm,
                                               const float* __restrict__ bias1,
                                               const float* __restrict__ bias2,
                                               ushort* __restrict__ C,
                                               int Nt, int Nn) {
    __shared__ ushort sA[128 * 32];
    __shared__ ushort sB[128 * 32];
    const int tid = threadIdx.x;
    const int lane = tid & 63, wv = tid >> 6;
    const int tm = blockIdx.x / Nt, tn = blockIdx.x % Nt;
    const int wm = wv >> 1, wn = wv & 1;

    const ushort* gA = A + (size_t)(tm * 128 + (tid >> 2)) * K + (tid & 3) * 8;
    const ushort* gB = Bm + (size_t)(tn * 128 + (tid >> 2)) * K + (tid & 3) * 8;
    char* lAb = (char*)sA + wv * 1024;
    char* lBb = (char*)sB + wv * 1024;

    f32x4 acc[4][4] = {};

    for (int kt = 0; kt < K / 32; kt++) {
        const ushort* a0 = gA + kt * 32;
        const ushort* b0 = gB + kt * 32;
        gload16(a0, lAb);
        gload16(a0 + 64 * K, lAb + 4096);
        gload16(b0, lBb);
        gload16(b0 + 64 * K, lBb + 4096);
        __syncthreads();

        bf16x8 af[4], bfv[4];
#pragma unroll
        for (int i = 0; i < 4; i++)
            af[i] = *(const bf16x8*)&sA[(wm * 64 + i * 16 + (lane & 15)) * 32 + (lane >> 4) * 8];
#pragma unroll
        for (int j = 0; j < 4; j++)
            bfv[j] = *(const bf16x8*)&sB[(wn * 64 + j * 16 + (lane & 15)) * 32 + (lane >> 4) * 8];
#pragma unroll
        for (int i = 0; i < 4; i++)
#pragma unroll
            for (int j = 0; j < 4; j++)
                acc[i][j] = __builtin_amdgcn_mfma_f32_16x16x32_bf16(af[i], bfv[j], acc[i][j], 0, 0, 0);
        __syncthreads();
    }

#pragma unroll
    for (int j = 0; j < 4; j++) {
        int n = tn * 128 + wn * 64 + j * 16 + (lane & 15);
        float bias = bias1[n] + (bias2 ? bias2[n] : 0.f);
#pragma unroll
        for (int i = 0; i < 4; i++) {
            int mbase = tm * 128 + wm * 64 + i * 16 + (lane >> 4) * 4;
#pragma unroll
            for (int r = 0; r < 4; r++) {
                float v = acc[i][j][r] + bias;
                if (RELU) v = v > 0.f ? v : 0.f;
                C[(size_t)(mbase + r) * Nn + n] = f2bf(v);
            }
        }
    }
}

// ---------------- persistent LSTM recurrence — r8 kernel + arrival-counter barrier ----------------
// 256 blocks = 4 batch-tiles x 64 hid-tiles, 1 block/CU, 4 waves (wave = gate).
// ONLY change vs the proven 612us round-8 kernel: the 64-flag x 64-lane poll sweep is
// replaced by ONE atomicAdd per block per step into cnt[bt][t] (fresh counter per step,
// 64B-padded) + a single-address poll by wave 0 (same-address loads coalesce/broadcast).
// Protocol transaction count per step drops ~64x; h-store path and ordering unchanged:
// agent stores -> __syncthreads (per-wave vmcnt(0) drain) -> post -> poll -> sync.
__global__ __launch_bounds__(256, 1) void lstm_persist(ushort* __restrict__ hs,
                                                       const ushort* __restrict__ xg,
                                                       const ushort* __restrict__ Whh,
                                                       unsigned* __restrict__ cnt) {
    const int tid = threadIdx.x;
    const int lane = tid & 63;
    const int wv = tid >> 6;                 // wave index == gate index
    const int blk = (int)blockIdx.x;
    const int batch0 = (blk >> 6) * 32;
    const int hid0 = (blk & 63) * 16;
    const int bt = blk >> 6;                 // batch tile = sync group (64 blocks)

    // Whh B-fragments for gate wv, rows hid0..hid0+15, K=1024 -> 32 x bf16x8
    bf16x8 breg[32];
    {
        const ushort* br = Whh + (size_t)(wv * H_ + hid0 + (lane & 15)) * H_ + ((lane >> 4) * 8);
#pragma unroll
        for (int ks = 0; ks < 32; ks++) breg[ks] = *(const bf16x8*)(br + ks * 32);
#pragma unroll
        for (int ks = 0; ks < 32; ks++) asm volatile("" : "+v"(breg[ks]));
    }

    __shared__ float lg[4][32][16];

    const int grow = tid >> 3;               // 0..31 batch row within tile
    const int gjp = (tid & 7) * 2;           // even hidden col pair
    float c0 = 0.f, c1 = 0.f;

    const int b = batch0 + grow;
    const int jj = hid0 + gjp;
    const ushort* xrow = xg + ((size_t)(b * T_) << 12) + jj;   // advance by 4096/step

    for (int t = 0; t < T_; t++) {
        // issue xg loads early (hides HBM/L3 latency under MFMA)
        const ushort* xr = xrow + ((size_t)t << 12);
        uint xi = *(const uint*)(xr);
        uint xf = *(const uint*)(xr + 1024);
        uint xgv = *(const uint*)(xr + 2048);
        uint xo = *(const uint*)(xr + 3072);

        // gates_pre = h[t] @ Whh_tile^T
        const ushort* ar = hs + (size_t)t * (B_ * H_)
                         + (size_t)(batch0 + (lane & 15)) * H_ + ((lane >> 4) * 8);
        f32x4 acc0 = {}, acc1 = {};
#pragma unroll
        for (int ks = 0; ks < 32; ks++) {
            bf16x8 a0 = *(const bf16x8*)(ar + ks * 32);
            bf16x8 a1 = *(const bf16x8*)(ar + 16 * H_ + ks * 32);
            acc0 = __builtin_amdgcn_mfma_f32_16x16x32_bf16(a0, breg[ks], acc0, 0, 0, 0);
            acc1 = __builtin_amdgcn_mfma_f32_16x16x32_bf16(a1, breg[ks], acc1, 0, 0, 0);
        }
#pragma unroll
        for (int r = 0; r < 4; r++) {
            lg[wv][(lane >> 4) * 4 + r][lane & 15] = acc0[r];
            lg[wv][16 + (lane >> 4) * 4 + r][lane & 15] = acc1[r];
        }
        __syncthreads();

        // gate math: 2 adjacent hidden cols per thread
        {
            float pi0 = bf2f((ushort)(xi & 0xffff)) + lg[0][grow][gjp];
            float pi1 = bf2f((ushort)(xi >> 16)) + lg[0][grow][gjp + 1];
            float pf0 = bf2f((ushort)(xf & 0xffff)) + lg[1][grow][gjp];
            float pf1 = bf2f((ushort)(xf >> 16)) + lg[1][grow][gjp + 1];
            float pg0 = bf2f((ushort)(xgv & 0xffff)) + lg[2][grow][gjp];
            float pg1 = bf2f((ushort)(xgv >> 16)) + lg[2][grow][gjp + 1];
            float po0 = bf2f((ushort)(xo & 0xffff)) + lg[3][grow][gjp];
            float po1 = bf2f((ushort)(xo >> 16)) + lg[3][grow][gjp + 1];
            float si0 = 1.f / (1.f + expf(-pi0)), si1 = 1.f / (1.f + expf(-pi1));
            float sf0 = 1.f / (1.f + expf(-pf0)), sf1 = 1.f / (1.f + expf(-pf1));
            float tg0 = tanhf(pg0), tg1 = tanhf(pg1);
            float so0 = 1.f / (1.f + expf(-po0)), so1 = 1.f / (1.f + expf(-po1));
            c0 = sf0 * c0 + si0 * tg0;
            c1 = sf1 * c1 + si1 * tg1;
            uint hp = (uint)f2bf(so0 * tanhf(c0)) | ((uint)f2bf(so1 * tanhf(c1)) << 16);
            unsigned* hp32 = (unsigned*)(hs + (size_t)(t + 1) * (B_ * H_) + (size_t)b * H_ + jj);
            // agent-scope store: write-through to L3, visible to all XCDs (r3/r8 proven)
            __hip_atomic_store(hp32, hp, __ATOMIC_RELAXED, __HIP_MEMORY_SCOPE_AGENT);
        }
        __syncthreads();   // per-wave vmcnt(0) before s_barrier: all h stores ACK'd

        if (t < T_ - 1) {
            unsigned* cp = cnt + ((size_t)(bt * T_ + t) << 4);   // 64B-padded counter
            if (tid == 0)
                atomicAdd(cp, 1u);          // device-scope arrival post (one per block)
            if (wv == 0) {
                // single-address poll: one fabric transaction per sweep (broadcast)
                for (;;) {
                    unsigned v = __hip_atomic_load(cp, __ATOMIC_RELAXED,
                                                   __HIP_MEMORY_SCOPE_AGENT);
                    if (v >= 64u) break;
                    __builtin_amdgcn_s_sleep(1);
                }
            }
            __syncthreads();
        }
    }
}

// ---------------- final classifier via MFMA: out[8192][22] = hs @ Wcb^T + bc ----------------
__global__ __launch_bounds__(256) void scores_mfma(const ushort* __restrict__ hs,
                                                   const ushort* __restrict__ Wcb,
                                                   const float* __restrict__ bc,
                                                   float* __restrict__ out) {
    const int tid = threadIdx.x, lane = tid & 63, w = tid >> 6;
    const int r0 = blockIdx.x * 64 + w * 16;
    const int rr = r0 + (lane & 15);          // output row = b*64 + t
    const int b = rr >> 6, t = rr & 63;
    const ushort* arow = hs + (size_t)(t + 1) * (B_ * H_) + (size_t)b * H_ + ((lane >> 4) * 8);
    const ushort* brow0 = Wcb + (size_t)(lane & 15) * H_ + ((lane >> 4) * 8);
    const ushort* brow1 = brow0 + 16 * H_;

    f32x4 acc0 = {}, acc1 = {};
#pragma unroll
    for (int ks = 0; ks < 32; ks++) {
        bf16x8 a  = *(const bf16x8*)(arow + ks * 32);
        bf16x8 p0 = *(const bf16x8*)(brow0 + ks * 32);
        bf16x8 p1 = *(const bf16x8*)(brow1 + ks * 32);
        acc0 = __builtin_amdgcn_mfma_f32_16x16x32_bf16(a, p0, acc0, 0, 0, 0);
        acc1 = __builtin_amdgcn_mfma_f32_16x16x32_bf16(a, p1, acc1, 0, 0, 0);
    }
#pragma unroll
    for (int nf = 0; nf < 2; nf++) {
        int c = nf * 16 + (lane & 15);
        if (c < C_) {
            float bias = bc[c];
            f32x4 acc = nf ? acc1 : acc0;
#pragma unroll
            for (int r = 0; r < 4; r++) {
                int row = r0 + (lane >> 4) * 4 + r;
                out[(size_t)row * C_ + c] = acc[r] + bias;
            }
        }
    }
}

extern "C" void kernel_launch(void* const* d_in, const int* in_sizes, int n_in,
                              void* d_out, int out_size, void* d_ws, size_t ws_size,
                              hipStream_t stream) {
    const float* x = (const float*)d_in[0];
    const float* W1 = (const float*)d_in[1];
    const float* b1 = (const float*)d_in[2];
    const float* W_ih = (const float*)d_in[3];
    const float* b_ih = (const float*)d_in[4];
    const float* W_hh = (const float*)d_in[5];
    const float* b_hh = (const float*)d_in[6];
    const float* Wc = (const float*)d_in[7];
    const float* bc = (const float*)d_in[8];
    float* out = (float*)d_out;

    char* ws = (char*)d_ws;
    ushort* Xb   = (ushort*)(ws);                 // 33,554,432 B  [8192][2048] bf16
    ushort* W1b  = (ushort*)(ws + 33554432);      //  4,194,304 B
    ushort* Wihb = (ushort*)(ws + 37748736);      //  8,388,608 B
    ushort* Whhb = (ushort*)(ws + 46137344);      //  8,388,608 B
    ushort* z    = (ushort*)(ws + 54525952);      // 16,777,216 B  [8192][1024]
    ushort* xg   = (ushort*)(ws + 71303168);      // 67,108,864 B  [8192][4096]
    ushort* hs   = (ushort*)(ws + 138412032);     // 17,039,360 B  [65][128][1024]
    ushort* Wcb  = (ushort*)(ws + 155451392);     //     65,536 B  [32][1024] bf16
    unsigned* cnt = (unsigned*)(ws + 155516928);  //     32,768 B  [4 groups][64 steps] 64B-padded
    // total ws use: ~155.6 MB

    hipMemsetAsync(hs, 0, (size_t)B_ * H_ * sizeof(ushort), stream);   // h0 = 0
    hipMemsetAsync(cnt, 0, 32768, stream);                             // arrival counters = 0

    cvt_f32_bf16<<<16384, 256, 0, stream>>>(x, Xb, 4194304);
    cvt_f32_bf16<<<2048, 256, 0, stream>>>(W1, W1b, 524288);
    cvt_f32_bf16<<<4096, 256, 0, stream>>>(W_ih, Wihb, 1048576);
    cvt_f32_bf16<<<4096, 256, 0, stream>>>(W_hh, Whhb, 1048576);
    cvt_wc<<<128, 256, 0, stream>>>(Wc, Wcb);

    // z = relu(x @ W1^T + b1)                 M=8192 N=1024 K=2048
    gemm_bt<2048, true><<<512, 256, 0, stream>>>(Xb, W1b, b1, nullptr, z, 8, 1024);
    // xg = z @ W_ih^T + (b_ih + b_hh)         M=8192 N=4096 K=1024
    gemm_bt<1024, false><<<2048, 256, 0, stream>>>(z, Wihb, b_ih, b_hh, xg, 32, 4096);

    // recurrence: r8 geometry (256 blocks x 256 thr, 1 blk/CU), arrival-counter barrier
    lstm_persist<<<256, 256, 0, stream>>>(hs, xg, Whhb, cnt);

    scores_mfma<<<128, 256, 0, stream>>>(hs, Wcb, bc, out);
}